// Round 13
// baseline (295.395 us; speedup 1.0000x reference)
//
#include <hip/hip_runtime.h>

// Problem dims
#define B_   256
#define N_   16000
#define C_   32
#define K_   64
#define T_   124
#define NJ   125      // 128-sample half-window block sums, j = 0..124
#define HID_ 50
#define OUT_ 10
#define TB_  1024     // snnB block size
#define CURS 52       // padded stride for cur/icur (float4-aligned)
#define WBS  324      // sWb row stride (float4-aligned)

typedef unsigned int u32;
typedef float v2f __attribute__((ext_vector_type(2)));
struct __align__(16) f2x2 { v2f lo, hi; };

// Exact single f32 ops (prevent fma contraction / reassociation).
__device__ __forceinline__ float fadd(float a, float b) { return __fadd_rn(a, b); }
__device__ __forceinline__ float fmul(float a, float b) { return __fmul_rn(a, b); }
__device__ __forceinline__ float fsub(float a, float b) { return __fsub_rn(a, b); }

// Packed f32 FMA, tap broadcast via VOP3P op_sel; taps in SGPRs.
__device__ __forceinline__ void PKFMA(v2f& y, v2f a, const f2x2& T, int k) {
    switch (k) {
    case 0:  asm("v_pk_fma_f32 %0, %1, %2, %0 op_sel:[0,0,0] op_sel_hi:[1,0,1]"
                 : "+v"(y) : "v"(a), "s"(T.lo)); break;
    case 1:  asm("v_pk_fma_f32 %0, %1, %2, %0 op_sel:[0,1,0] op_sel_hi:[1,1,1]"
                 : "+v"(y) : "v"(a), "s"(T.lo)); break;
    case 2:  asm("v_pk_fma_f32 %0, %1, %2, %0 op_sel:[0,0,0] op_sel_hi:[1,0,1]"
                 : "+v"(y) : "v"(a), "s"(T.hi)); break;
    default: asm("v_pk_fma_f32 %0, %1, %2, %0 op_sel:[0,1,0] op_sel_hi:[1,1,1]"
                 : "+v"(y) : "v"(a), "s"(T.hi)); break;
    }
}

// ---------------------------------------------------------------------------
// Kernel A: r21 structure (measured 177-184 us, VGPR 52, no spills; ~89% of
// the 103 TF sustained FMA ceiling). Do not touch.
// ---------------------------------------------------------------------------
__global__ __launch_bounds__(256, 4) void convA(const float* __restrict__ audio,
                                                const float* __restrict__ gt,
                                                float* __restrict__ Sg) {
    __shared__ __align__(16) float abI[1280];
    __shared__ __align__(16) float ybuf[4][4][272];

    const int b = blockIdx.x, g = blockIdx.y;
    const int tid = threadIdx.x, w = tid >> 6, lane = tid & 63;
    const float* arow = audio + (size_t)b * N_;

    const int origin = (g << 10) - 32;
    for (int idx = tid; idx < 1280; idx += 256) {
        int P = idx / 640, j = idx - P * 640;
        int ii = j >> 1, h = j & 1;
        int gi = origin + (P << 9) + (h << 8) + ii;
        float v = (gi >= 0 && gi < N_) ? arow[gi] : 0.0f;
        abI[P * 640 + (j ^ (((j >> 5) & 1) << 2))] = v;
    }
    __syncthreads();

    for (int G = 0; G < 2; ++G) {
        const int rowbase = __builtin_amdgcn_readfirstlane(((w << 3) + (G << 2)) << 6);
        const float* kg = gt + rowbase;

        v2f Y[2][4][4];
#pragma unroll
        for (int P = 0; P < 2; ++P)
#pragma unroll
            for (int ch = 0; ch < 4; ++ch)
#pragma unroll
                for (int d = 0; d < 4; ++d) { Y[P][ch][d].x = 0.0f; Y[P][ch][d].y = 0.0f; }

        // ---- q = 0 peel
        {
            f2x2 Tc[4];
#pragma unroll
            for (int ch = 0; ch < 4; ++ch)
                Tc[ch] = *(const f2x2*)(kg + (ch << 6));
            const int u = lane;
            const int p1 = (u << 3) ^ (((u >> 2) & 1) << 2);
#pragma unroll
            for (int P = 0; P < 2; ++P) {
                const float* abP = abI + P * 640;
                const f2x2 A0 = *(const f2x2*)(abP + p1);
                const f2x2 A1 = *(const f2x2*)(abP + (p1 ^ 4));
#pragma unroll
                for (int e = 0; e < 4; ++e) {
                    const v2f a = (e == 0) ? A0.lo : (e == 1) ? A0.hi
                                : (e == 2) ? A1.lo : A1.hi;
#pragma unroll
                    for (int ch = 0; ch < 4; ++ch)
#pragma unroll
                        for (int d = 0; d < 4; ++d) {
                            const int kb = e - 1 - d;
                            if (kb >= 0) PKFMA(Y[P][ch][d], a, Tc[ch], kb);
                        }
                }
            }
        }

        // ---- q = 1..15
#pragma unroll 1
        for (int q = 1; q < 16; ++q) {
            f2x2 Tm[4], Tc[4];
#pragma unroll
            for (int ch = 0; ch < 4; ++ch) {
                Tm[ch] = *(const f2x2*)(kg + (ch << 6) + ((q - 1) << 2));
                Tc[ch] = *(const f2x2*)(kg + (ch << 6) + (q << 2));
            }
            const int u = lane + q;
            const int p1 = (u << 3) ^ (((u >> 2) & 1) << 2);
#pragma unroll
            for (int P = 0; P < 2; ++P) {
                const float* abP = abI + P * 640;
                const f2x2 A0 = *(const f2x2*)(abP + p1);
                const f2x2 A1 = *(const f2x2*)(abP + (p1 ^ 4));
#pragma unroll
                for (int e = 0; e < 4; ++e) {
                    const v2f a = (e == 0) ? A0.lo : (e == 1) ? A0.hi
                                : (e == 2) ? A1.lo : A1.hi;
#pragma unroll
                    for (int ch = 0; ch < 4; ++ch)
#pragma unroll
                        for (int d = 0; d < 4; ++d) {
                            const int ts = e - 1 - d;
                            if (ts >= 0) PKFMA(Y[P][ch][d], a, Tc[ch], ts);
                            else         PKFMA(Y[P][ch][d], a, Tm[ch], 4 + ts);
                        }
                }
            }
        }

        // ---- q = 16 peel
        {
            f2x2 Tm[4];
#pragma unroll
            for (int ch = 0; ch < 4; ++ch)
                Tm[ch] = *(const f2x2*)(kg + (ch << 6) + 60);
            const int u = lane + 16;
            const int p1 = (u << 3) ^ (((u >> 2) & 1) << 2);
#pragma unroll
            for (int P = 0; P < 2; ++P) {
                const float* abP = abI + P * 640;
                const f2x2 A0 = *(const f2x2*)(abP + p1);
                const f2x2 A1 = *(const f2x2*)(abP + (p1 ^ 4));
#pragma unroll
                for (int e = 0; e < 4; ++e) {
                    const v2f a = (e == 0) ? A0.lo : (e == 1) ? A0.hi
                                : (e == 2) ? A1.lo : A1.hi;
#pragma unroll
                    for (int ch = 0; ch < 4; ++ch)
#pragma unroll
                        for (int d = 0; d < 4; ++d) {
                            const int ts = e - 1 - d;
                            if (ts < 0) PKFMA(Y[P][ch][d], a, Tm[ch], 4 + ts);
                        }
                }
            }
        }

        // ---- epilogue per pp
#pragma unroll
        for (int pp = 0; pp < 4; ++pp) {
            const int P = pp >> 1, h = pp & 1;
#pragma unroll
            for (int ch = 0; ch < 4; ++ch) {
                float4 z;
                z.x = fmaxf(h ? Y[P][ch][0].y : Y[P][ch][0].x, 0.0f);
                z.y = fmaxf(h ? Y[P][ch][1].y : Y[P][ch][1].x, 0.0f);
                z.z = fmaxf(h ? Y[P][ch][2].y : Y[P][ch][2].x, 0.0f);
                z.w = fmaxf(h ? Y[P][ch][3].y : Y[P][ch][3].x, 0.0f);
                *(float4*)(&ybuf[w][ch][((lane >> 5) * 136) + ((lane & 31) << 2)]) = z;
            }
            {
                const int ch2 = lane >> 4, blk = (lane >> 3) & 1, j = lane & 7;
                const float* yb = &ybuf[w][ch2][blk * 136 + j];
                float r = yb[0];
#pragma unroll
                for (int m = 1; m < 16; ++m) r = fadd(r, yb[m << 3]);
                float v = fadd(r, __shfl_xor(r, 1));
                v = fadd(v, __shfl_xor(v, 2));
                v = fadd(v, __shfl_xor(v, 4));
                const int jg = (g << 3) + (pp << 1) + blk;
                const int c = (w << 3) + (G << 2) + ch2;
                if (j == 0 && jg < NJ) Sg[((size_t)b * C_ + c) * NJ + jg] = v;
            }
        }
    }
}

// ---------------------------------------------------------------------------
// Kernel B: exact round-7 snnB (best measured total: 285.94 us). Flat phase
// structure; float4-staged sWb; t-quad x h-pair current phases; batch-8
// membrane chains. All per-output accumulation orders reference-identical.
// ---------------------------------------------------------------------------
__global__ __launch_bounds__(TB_, 1) void snnB(const float* __restrict__ Sg,
                                               const float* __restrict__ Wb,
                                               const float* __restrict__ Wic,
                                               const float* __restrict__ Wac,
                                               float* __restrict__ out) {
    __shared__ __align__(16) float sWb[HID_ * WBS];   // 64,800 B
    __shared__ __align__(16) float sWic[HID_ * 52];   // 10,400 B
    __shared__ __align__(16) float sWac[OUT_ * 52];   //  2,080 B
    __shared__ u32   mask[128 * 10];                  //  5,120 B (rows 124..127 zero)
    __shared__ __align__(16) float cur[T_ * CURS];    // 25,792 B
    __shared__ __align__(16) float icur[T_ * CURS];   // 25,792 B
    __shared__ float acur[T_ * 12];                   //  5,952 B  (total ~139.9 KB)

    const int b = blockIdx.x, tid = threadIdx.x;

    // sWb: float4 staging (320 % 4 == 0 -> each float4 within one row)
    for (int i4 = tid; i4 < 4000; i4 += TB_) {
        const int i = i4 << 2;
        const int r = i / 320, col = i - r * 320;
        *(float4*)(&sWb[r * WBS + col]) = *(const float4*)(Wb + i);
    }
    for (int i = tid; i < HID_ * HID_; i += TB_) {
        int r = i / 50;
        sWic[r * 52 + (i - r * 50)] = Wic[i];
    }
    for (int i = tid; i < OUT_ * HID_; i += TB_) {
        int r = i / 50;
        sWac[r * 52 + (i - r * 50)] = Wac[i];
    }

    // ---- AN spike bitmasks: word (t, wd) covers i in [32wd, 32wd+32)
    const float* Sb = Sg + (size_t)b * C_ * NJ;
    for (int idx = tid; idx < 1280; idx += TB_) {
        if (idx >= T_ * 10) { mask[idx] = 0; continue; }
        int t = idx / 10, wd = idx - t * 10;
        u32 m = 0;
        int c_prev = -1;
        float env = 0.0f;
        for (int k = 0; k < 32; ++k) {
            int i = wd * 32 + k;
            int c = i / 10, s = i - c * 10;
            if (c != c_prev) {
                env = fmul(fadd(Sb[c * NJ + t], Sb[c * NJ + t + 1]), 0.00390625f);
                c_prev = c;
            }
            float sf = (s == 9) ? 1.5f : (float)(0.5 + (double)s * (1.0 / 9.0));
            if (fsub(fmul(env, sf), 0.5f) > 0.0f) m |= (1u << k);
        }
        mask[idx] = m;
    }
    __syncthreads();

    // ---- Bushy currents: t-quad (t0+{0,31,62,93}) x h-pair (hp, hp+25)
    if (tid < 31 * 25) {
        const int t0 = tid / 25, hp = tid - t0 * 25;
        const float* wr0 = sWb + hp * WBS;
        const float* wr1 = sWb + (hp + 25) * WBS;
        const u32* mrow = mask + t0 * 10;
        v2f a0 = {0.0f, 0.0f}, a1 = {0.0f, 0.0f};   // x = h=hp, y = h=hp+25
        v2f a2 = {0.0f, 0.0f}, a3 = {0.0f, 0.0f};
#pragma unroll 1
        for (int wi = 0; wi < 10; ++wi) {
            const u32 w0 = mrow[wi],       w1 = mrow[310 + wi];
            const u32 w2 = mrow[620 + wi], w3 = mrow[930 + wi];
#pragma unroll
            for (int b2 = 0; b2 < 32; ++b2) {
                const int i = (wi << 5) + b2;
                const int iw0 = __float_as_int(wr0[i]);
                const int iw1 = __float_as_int(wr1[i]);
                const int s0 = __builtin_amdgcn_sbfe((int)w0, b2, 1);
                const int s1 = __builtin_amdgcn_sbfe((int)w1, b2, 1);
                const int s2 = __builtin_amdgcn_sbfe((int)w2, b2, 1);
                const int s3 = __builtin_amdgcn_sbfe((int)w3, b2, 1);
                v2f p0, p1, p2, p3;
                p0.x = __int_as_float(iw0 & s0);  p0.y = __int_as_float(iw1 & s0);
                p1.x = __int_as_float(iw0 & s1);  p1.y = __int_as_float(iw1 & s1);
                p2.x = __int_as_float(iw0 & s2);  p2.y = __int_as_float(iw1 & s2);
                p3.x = __int_as_float(iw0 & s3);  p3.y = __int_as_float(iw1 & s3);
                a0 = a0 + p0;   // v_pk_add_f32: each half IEEE fadd (+0.0 on clear)
                a1 = a1 + p1;
                a2 = a2 + p2;
                a3 = a3 + p3;
            }
        }
        cur[(t0     ) * CURS + hp] = a0.x;  cur[(t0     ) * CURS + hp + 25] = a0.y;
        cur[(t0 + 31) * CURS + hp] = a1.x;  cur[(t0 + 31) * CURS + hp + 25] = a1.y;
        cur[(t0 + 62) * CURS + hp] = a2.x;  cur[(t0 + 62) * CURS + hp + 25] = a2.y;
        cur[(t0 + 93) * CURS + hp] = a3.x;  cur[(t0 + 93) * CURS + hp + 25] = a3.y;
    }
    __syncthreads();

    // ---- Bushy membrane chains: batch-8 prefetch, serial chain in regs
    if (tid < HID_) {
        float mem = 0.0f;
        for (int t0 = 0; t0 < 120; t0 += 8) {
            float c0[8];
#pragma unroll
            for (int k = 0; k < 8; ++k) c0[k] = cur[(t0 + k) * CURS + tid];
#pragma unroll
            for (int k = 0; k < 8; ++k) {
                float m = fadd(fmul(0.95f, mem), c0[k]);
                float sp = (fsub(m, 1.0f) > 0.0f) ? 1.0f : 0.0f;
                mem = fsub(m, sp);
                cur[(t0 + k) * CURS + tid] = sp;
            }
        }
        for (int t = 120; t < T_; ++t) {
            float m = fadd(fmul(0.95f, mem), cur[t * CURS + tid]);
            float sp = (fsub(m, 1.0f) > 0.0f) ? 1.0f : 0.0f;
            mem = fsub(m, sp);
            cur[t * CURS + tid] = sp;
        }
    }
    __syncthreads();

    // ---- IC currents: t-quad x h-pair, g4-outer (weights read once/8 out)
    if (tid < 31 * 25) {
        const int t0 = tid / 25, hp = tid - t0 * 25;
        const float* w0 = sWic + hp * 52;
        const float* w1 = sWic + (hp + 25) * 52;
        const float* sb0 = cur + (t0     ) * CURS;
        const float* sb1 = cur + (t0 + 31) * CURS;
        const float* sb2 = cur + (t0 + 62) * CURS;
        const float* sb3 = cur + (t0 + 93) * CURS;
        float A00 = 0.0f, A01 = 0.0f, A10 = 0.0f, A11 = 0.0f;
        float A20 = 0.0f, A21 = 0.0f, A30 = 0.0f, A31 = 0.0f;
#pragma unroll
        for (int g4 = 0; g4 < 12; ++g4) {
            const float4 wa = *(const float4*)(w0 + (g4 << 2));
            const float4 wb = *(const float4*)(w1 + (g4 << 2));
            const float4 s0 = *(const float4*)(sb0 + (g4 << 2));
            const float4 s1 = *(const float4*)(sb1 + (g4 << 2));
            const float4 s2 = *(const float4*)(sb2 + (g4 << 2));
            const float4 s3 = *(const float4*)(sb3 + (g4 << 2));
            A00 = fmaf(s0.x, wa.x, A00); A00 = fmaf(s0.y, wa.y, A00);
            A00 = fmaf(s0.z, wa.z, A00); A00 = fmaf(s0.w, wa.w, A00);
            A01 = fmaf(s0.x, wb.x, A01); A01 = fmaf(s0.y, wb.y, A01);
            A01 = fmaf(s0.z, wb.z, A01); A01 = fmaf(s0.w, wb.w, A01);
            A10 = fmaf(s1.x, wa.x, A10); A10 = fmaf(s1.y, wa.y, A10);
            A10 = fmaf(s1.z, wa.z, A10); A10 = fmaf(s1.w, wa.w, A10);
            A11 = fmaf(s1.x, wb.x, A11); A11 = fmaf(s1.y, wb.y, A11);
            A11 = fmaf(s1.z, wb.z, A11); A11 = fmaf(s1.w, wb.w, A11);
            A20 = fmaf(s2.x, wa.x, A20); A20 = fmaf(s2.y, wa.y, A20);
            A20 = fmaf(s2.z, wa.z, A20); A20 = fmaf(s2.w, wa.w, A20);
            A21 = fmaf(s2.x, wb.x, A21); A21 = fmaf(s2.y, wb.y, A21);
            A21 = fmaf(s2.z, wb.z, A21); A21 = fmaf(s2.w, wb.w, A21);
            A30 = fmaf(s3.x, wa.x, A30); A30 = fmaf(s3.y, wa.y, A30);
            A30 = fmaf(s3.z, wa.z, A30); A30 = fmaf(s3.w, wa.w, A30);
            A31 = fmaf(s3.x, wb.x, A31); A31 = fmaf(s3.y, wb.y, A31);
            A31 = fmaf(s3.z, wb.z, A31); A31 = fmaf(s3.w, wb.w, A31);
        }
        A00 = fmaf(sb0[48], w0[48], A00); A00 = fmaf(sb0[49], w0[49], A00);
        A01 = fmaf(sb0[48], w1[48], A01); A01 = fmaf(sb0[49], w1[49], A01);
        A10 = fmaf(sb1[48], w0[48], A10); A10 = fmaf(sb1[49], w0[49], A10);
        A11 = fmaf(sb1[48], w1[48], A11); A11 = fmaf(sb1[49], w1[49], A11);
        A20 = fmaf(sb2[48], w0[48], A20); A20 = fmaf(sb2[49], w0[49], A20);
        A21 = fmaf(sb2[48], w1[48], A21); A21 = fmaf(sb2[49], w1[49], A21);
        A30 = fmaf(sb3[48], w0[48], A30); A30 = fmaf(sb3[49], w0[49], A30);
        A31 = fmaf(sb3[48], w1[48], A31); A31 = fmaf(sb3[49], w1[49], A31);
        icur[(t0     ) * CURS + hp] = A00;  icur[(t0     ) * CURS + hp + 25] = A01;
        icur[(t0 + 31) * CURS + hp] = A10;  icur[(t0 + 31) * CURS + hp + 25] = A11;
        icur[(t0 + 62) * CURS + hp] = A20;  icur[(t0 + 62) * CURS + hp + 25] = A21;
        icur[(t0 + 93) * CURS + hp] = A30;  icur[(t0 + 93) * CURS + hp + 25] = A31;
    }
    __syncthreads();

    // ---- IC membrane chains: batch-8
    if (tid < HID_) {
        float mem = 0.0f;
        for (int t0 = 0; t0 < 120; t0 += 8) {
            float c0[8];
#pragma unroll
            for (int k = 0; k < 8; ++k) c0[k] = icur[(t0 + k) * CURS + tid];
#pragma unroll
            for (int k = 0; k < 8; ++k) {
                float m = fadd(fmul(0.95f, mem), c0[k]);
                float sp = (fsub(m, 1.0f) > 0.0f) ? 1.0f : 0.0f;
                mem = fsub(m, sp);
                icur[(t0 + k) * CURS + tid] = sp;
            }
        }
        for (int t = 120; t < T_; ++t) {
            float m = fadd(fmul(0.95f, mem), icur[t * CURS + tid]);
            float sp = (fsub(m, 1.0f) > 0.0f) ? 1.0f : 0.0f;
            mem = fsub(m, sp);
            icur[t * CURS + tid] = sp;
        }
    }
    __syncthreads();

    // ---- AC currents: t-quad x o-pair (155 threads), g4-outer
    if (tid < 31 * 5) {
        const int t0 = tid / 5, op = tid - t0 * 5;
        const float* w0 = sWac + op * 52;
        const float* w1 = sWac + (op + 5) * 52;
        const float* sb0 = icur + (t0     ) * CURS;
        const float* sb1 = icur + (t0 + 31) * CURS;
        const float* sb2 = icur + (t0 + 62) * CURS;
        const float* sb3 = icur + (t0 + 93) * CURS;
        float A00 = 0.0f, A01 = 0.0f, A10 = 0.0f, A11 = 0.0f;
        float A20 = 0.0f, A21 = 0.0f, A30 = 0.0f, A31 = 0.0f;
#pragma unroll
        for (int g4 = 0; g4 < 12; ++g4) {
            const float4 wa = *(const float4*)(w0 + (g4 << 2));
            const float4 wb = *(const float4*)(w1 + (g4 << 2));
            const float4 s0 = *(const float4*)(sb0 + (g4 << 2));
            const float4 s1 = *(const float4*)(sb1 + (g4 << 2));
            const float4 s2 = *(const float4*)(sb2 + (g4 << 2));
            const float4 s3 = *(const float4*)(sb3 + (g4 << 2));
            A00 = fmaf(s0.x, wa.x, A00); A00 = fmaf(s0.y, wa.y, A00);
            A00 = fmaf(s0.z, wa.z, A00); A00 = fmaf(s0.w, wa.w, A00);
            A01 = fmaf(s0.x, wb.x, A01); A01 = fmaf(s0.y, wb.y, A01);
            A01 = fmaf(s0.z, wb.z, A01); A01 = fmaf(s0.w, wb.w, A01);
            A10 = fmaf(s1.x, wa.x, A10); A10 = fmaf(s1.y, wa.y, A10);
            A10 = fmaf(s1.z, wa.z, A10); A10 = fmaf(s1.w, wa.w, A10);
            A11 = fmaf(s1.x, wb.x, A11); A11 = fmaf(s1.y, wb.y, A11);
            A11 = fmaf(s1.z, wb.z, A11); A11 = fmaf(s1.w, wb.w, A11);
            A20 = fmaf(s2.x, wa.x, A20); A20 = fmaf(s2.y, wa.y, A20);
            A20 = fmaf(s2.z, wa.z, A20); A20 = fmaf(s2.w, wa.w, A20);
            A21 = fmaf(s2.x, wb.x, A21); A21 = fmaf(s2.y, wb.y, A21);
            A21 = fmaf(s2.z, wb.z, A21); A21 = fmaf(s2.w, wb.w, A21);
            A30 = fmaf(s3.x, wa.x, A30); A30 = fmaf(s3.y, wa.y, A30);
            A30 = fmaf(s3.z, wa.z, A30); A30 = fmaf(s3.w, wa.w, A30);
            A31 = fmaf(s3.x, wb.x, A31); A31 = fmaf(s3.y, wb.y, A31);
            A31 = fmaf(s3.z, wb.z, A31); A31 = fmaf(s3.w, wb.w, A31);
        }
        A00 = fmaf(sb0[48], w0[48], A00); A00 = fmaf(sb0[49], w0[49], A00);
        A01 = fmaf(sb0[48], w1[48], A01); A01 = fmaf(sb0[49], w1[49], A01);
        A10 = fmaf(sb1[48], w0[48], A10); A10 = fmaf(sb1[49], w0[49], A10);
        A11 = fmaf(sb1[48], w1[48], A11); A11 = fmaf(sb1[49], w1[49], A11);
        A20 = fmaf(sb2[48], w0[48], A20); A20 = fmaf(sb2[49], w0[49], A20);
        A21 = fmaf(sb2[48], w1[48], A21); A21 = fmaf(sb2[49], w1[49], A21);
        A30 = fmaf(sb3[48], w0[48], A30); A30 = fmaf(sb3[49], w0[49], A30);
        A31 = fmaf(sb3[48], w1[48], A31); A31 = fmaf(sb3[49], w1[49], A31);
        acur[(t0     ) * 12 + op] = A00;  acur[(t0     ) * 12 + op + 5] = A01;
        acur[(t0 + 31) * 12 + op] = A10;  acur[(t0 + 31) * 12 + op + 5] = A11;
        acur[(t0 + 62) * 12 + op] = A20;  acur[(t0 + 62) * 12 + op + 5] = A21;
        acur[(t0 + 93) * 12 + op] = A30;  acur[(t0 + 93) * 12 + op + 5] = A31;
    }
    __syncthreads();

    // ---- AC membrane chains + output stores: batch-8
    if (tid < OUT_) {
        float mem = 0.0f;
        for (int t0 = 0; t0 < 120; t0 += 8) {
            float c0[8];
#pragma unroll
            for (int k = 0; k < 8; ++k) c0[k] = acur[(t0 + k) * 12 + tid];
#pragma unroll
            for (int k = 0; k < 8; ++k) {
                float m = fadd(fmul(0.95f, mem), c0[k]);
                float sp = (fsub(m, 1.0f) > 0.0f) ? 1.0f : 0.0f;
                float mo = fsub(m, sp);
                mem = mo;
                size_t base = ((size_t)b * T_ + (t0 + k)) * OUT_ + tid;
                out[base] = sp;
                out[(size_t)(B_ * T_ * OUT_) + base] = mo;
            }
        }
        for (int t = 120; t < T_; ++t) {
            float m = fadd(fmul(0.95f, mem), acur[t * 12 + tid]);
            float sp = (fsub(m, 1.0f) > 0.0f) ? 1.0f : 0.0f;
            float mo = fsub(m, sp);
            mem = mo;
            size_t base = ((size_t)b * T_ + t) * OUT_ + tid;
            out[base] = sp;
            out[(size_t)(B_ * T_ * OUT_) + base] = mo;
        }
    }
}

// ---------------------------------------------------------------------------
extern "C" void kernel_launch(void* const* d_in, const int* in_sizes, int n_in,
                              void* d_out, int out_size, void* d_ws, size_t ws_size,
                              hipStream_t stream) {
    (void)in_sizes; (void)n_in; (void)out_size; (void)ws_size;
    const float* audio = (const float*)d_in[0];
    const float* gt    = (const float*)d_in[1];
    const float* Wb    = (const float*)d_in[2];
    const float* Wic   = (const float*)d_in[3];
    const float* Wac   = (const float*)d_in[4];

    float* Sg = (float*)d_ws;   // needs 256*32*125*4 = 4,096,000 B of ws

    convA<<<dim3(B_, 16), dim3(256), 0, stream>>>(audio, gt, Sg);
    snnB<<<dim3(B_), dim3(TB_), 0, stream>>>(Sg, Wb, Wic, Wac, (float*)d_out);
}